// Round 10
// baseline (203.258 us; speedup 1.0000x reference)
//
#include <hip/hip_runtime.h>

// GCN 2-layer: x[N,128] -> GCNConv(W1[128,64], b1) -> ReLU -> GCNConv(W2[64,32], b2)
// norm = dinv[src]*dinv[dst] factorized. Bucketed multisplit build (R4), bf16
// intermediates (R5), MFMA gemms (R8), dense per-bucket edge segments (R10),
// pre-scaled hs (R11), group-per-node aggs (R12), batched gather issue (R13),
// rank capture (R14), pk-cvt + pre-converted W + 2-barrier scan (R15/R16),
// 512-node buckets + sentinel unconditional aggs (R17/R18), gemm2 fused into
// agg1 epilogue (R19).
// R20: agg accumulate via v_dot2_f32_bf16 (b=(1,0) extracts+adds lo bf16,
// b=(0,1) hi; bf16*1.0 exact in f32 -> bit-identical to unpack+add).
// 8 dot2 per gathered uint4 vs 12 unpack+pk_add ops: ~30% off the agg
// VALU stream (aggs are issue-bound per R12 arithmetic).

#define BLK 256
#define BLKC 1024        // k_csr block size
#define EPT 8            // edges/thread in k_part
#define CITER 10         // k_csr max edges/thread = SLOTB/BLKC
#define BSHIFT 9         // nodes per bucket
#define NPB 512          // 1 << BSHIFT
#define SLOTB 10240      // edge slots per bucket; lambda~8.2K, ~23 sigma
#define NBMAX 256        // >= nbuck = ceil(N/NPB) = 196

typedef unsigned int uint_t;
typedef unsigned short ushort_t;
typedef __attribute__((ext_vector_type(8))) short bf16x8;   // MFMA A/B frag
typedef __attribute__((ext_vector_type(4))) float f32x4;    // MFMA C/D frag

#define BLO 0x00003F80u   // bf16 pair (1.0, 0.0): selects lo half
#define BHI 0x3F800000u   // bf16 pair (0.0, 1.0): selects hi half

// paired RNE f32->bf16: lo -> bits[15:0], hi -> bits[31:16] (1 VALU op)
__device__ __forceinline__ uint_t pkbf(float lo, float hi) {
    uint_t r;
    asm("v_cvt_pk_bf16_f32 %0, %1, %2" : "=v"(r) : "v"(lo), "v"(hi));
    return r;
}

// s += selected bf16 half of packed pair v (1 VOP3P op; exact)
__device__ __forceinline__ void d2(float& s, uint_t v, uint_t sel) {
    asm("v_dot2_f32_bf16 %0, %1, %2, %0" : "+v"(s) : "v"(v), "v"(sel));
}

// 8 bf16 (uint4) += into 8 f32 accumulators via dot2 (8 ops, was 12)
__device__ __forceinline__ void dadd(float& s0, float& s1, float& s2, float& s3,
                                     float& s4, float& s5, float& s6, float& s7,
                                     uint4 v, uint_t blo, uint_t bhi) {
    d2(s0, v.x, blo); d2(s1, v.x, bhi);
    d2(s2, v.y, blo); d2(s3, v.y, bhi);
    d2(s4, v.z, blo); d2(s5, v.z, bhi);
    d2(s6, v.w, blo); d2(s7, v.w, bhi);
}

// int64-layout detection (wave-uniform, L2-hot)
__device__ __forceinline__ bool detect64(const int* __restrict__ idx) {
    int z = 0;
#pragma unroll
    for (int i = 1; i < 32; i += 2) z |= idx[i];
    return z == 0;
}

// ---- build pass 1: partition edges into DENSE per-bucket segments.
// Rank captured from the counting atomicAdd; placement pass has no atomics.
// Block PB (extra) converts W1->W1^T bf16 [64][128] and W2->W2^T bf16 [32][64].
__global__ void k_part(const int* __restrict__ idx, int* __restrict__ bcursor,
                       int* __restrict__ edge_part,
                       const float* __restrict__ W1, const float* __restrict__ W2,
                       ushort_t* __restrict__ wt, int E, int nbuck, int PB) {
    if (blockIdx.x == PB) {          // W-conversion block
        int t = threadIdx.x;
        int n = t >> 2, q = t & 3;   // W1^T row n (0..63), k-block q (32 k)
        uint_t buf[16];
#pragma unroll
        for (int i = 0; i < 16; ++i) {
            float a = W1[(size_t)(32 * q + 2 * i) * 64 + n];
            float b = W1[(size_t)(32 * q + 2 * i + 1) * 64 + n];
            buf[i] = pkbf(a, b);
        }
#pragma unroll
        for (int i = 0; i < 4; ++i)
            ((uint4*)wt)[(size_t)n * 16 + q * 4 + i] = *(uint4*)&buf[4 * i];
        if (t < 128) {               // W2^T row n2 (0..31), k-block q2 (16 k)
            int n2 = t >> 2, q2 = t & 3;
            uint_t b2[8];
#pragma unroll
            for (int i = 0; i < 8; ++i) {
                float a = W2[(size_t)(16 * q2 + 2 * i) * 32 + n2];
                float b = W2[(size_t)(16 * q2 + 2 * i + 1) * 32 + n2];
                b2[i] = pkbf(a, b);
            }
#pragma unroll
            for (int i = 0; i < 2; ++i)
                ((uint4*)(wt + 8192))[(size_t)n2 * 8 + q2 * 2 + i] = *(uint4*)&b2[4 * i];
        }
        return;
    }
    __shared__ int h[NBMAX];
    __shared__ int rb[NBMAX];
    bool is64 = detect64(idx);
    int t = threadIdx.x, blk = blockIdx.x;
    for (int i = t; i < nbuck; i += BLK) h[i] = 0;
    __syncthreads();
    int base = blk * (BLK * EPT) + t;
    int dst[EPT], src[EPT], rk[EPT];
#pragma unroll
    for (int k = 0; k < EPT; ++k) {
        int e = base + k * BLK;
        if (e < E) {
            if (is64) {
                uint2 dv = ((const uint2*)idx)[(size_t)E + e];   // int64 dst[e]
                uint2 sv = ((const uint2*)idx)[e];               // int64 src[e]
                dst[k] = (int)dv.x;
                src[k] = (int)sv.x;
            } else {
                dst[k] = idx[E + e];
                src[k] = idx[e];
            }
            rk[k] = atomicAdd(&h[dst[k] >> BSHIFT], 1);
        } else {
            dst[k] = -1;
        }
    }
    __syncthreads();
    for (int i = t; i < nbuck; i += BLK) {
        int c = h[i];
        rb[i] = c ? atomicAdd(&bcursor[i], c) : 0;
    }
    __syncthreads();
#pragma unroll
    for (int k = 0; k < EPT; ++k) {
        if (dst[k] >= 0) {
            int b = dst[k] >> BSHIFT;
            edge_part[(size_t)b * SLOTB + rb[b] + rk[k]] =
                src[k] | ((dst[k] & (NPB - 1)) << 17);
        }
    }
}

// ---- build pass 2: one 1024-thread block per 512-node bucket; emits
// row_ptr, deg, dinv, csr_src. Single edge sweep with rank capture;
// shfl wave-scan over 512 entries (2 barriers).
__global__ __launch_bounds__(BLKC) void k_csr(
        const int* __restrict__ edge_part, const int* __restrict__ bcursor,
        int* __restrict__ row_ptr, int* __restrict__ deg, float* __restrict__ dinv,
        int* __restrict__ csr_src, int N, int nbuck) {
    __shared__ int cnt[NPB];
    __shared__ int off[NPB];
    __shared__ int wsum[8];
    int b = blockIdx.x, t = threadIdx.x;
    int node0 = b << BSHIFT;
    int nn = min(NPB, N - node0);
    int m = bcursor[b];                   // total edges in this bucket
    size_t ebase = (size_t)b * SLOTB;
    if (t < NPB) cnt[t] = 0;
    __syncthreads();
    int pp[CITER], rr[CITER];
#pragma unroll
    for (int it = 0; it < CITER; ++it) {
        int e = t + it * BLKC;
        if (e < m) {
            int p = edge_part[ebase + e];
            pp[it] = p;
            rr[it] = atomicAdd(&cnt[((unsigned)p) >> 17], 1);
        }
    }
    __syncthreads();
    // scan over 512 entries: waves 0..7 shfl-scan, 8-entry wave-sum scan
    int cown = 0, xi = 0;
    if (t < NPB) {
        cown = cnt[t];
        xi = cown;
#pragma unroll
        for (int d = 1; d < 64; d <<= 1) {
            int y = __shfl_up(xi, d, 64);
            if ((t & 63) >= d) xi += y;
        }
        if ((t & 63) == 63) wsum[t >> 6] = xi;
    }
    __syncthreads();
    if (t < 8) {
        int wv = wsum[t];
#pragma unroll
        for (int d = 1; d < 8; d <<= 1) {
            int y = __shfl_up(wv, d, 64);
            if (t >= d) wv += y;
        }
        wsum[t] = wv;   // inclusive wave sums
    }
    __syncthreads();
    if (t < NPB) {
        int excl = xi - cown + ((t >= 64) ? wsum[(t >> 6) - 1] : 0);
        off[t] = excl;
        if (t < nn) {
            row_ptr[node0 + t] = (int)(ebase + excl);
            deg[node0 + t] = cown;
            dinv[node0 + t] = rsqrtf((float)(cown + 1));  // +1 self-loop
        }
    }
    __syncthreads();
#pragma unroll
    for (int it = 0; it < CITER; ++it) {
        int e = t + it * BLKC;
        if (e < m) {
            int p = pp[it];
            int dlo = ((unsigned)p) >> 17;
            csr_src[ebase + off[dlo] + rr[it]] = p & 0x1FFFF;
        }
    }
}

// ---- layer 1 GEMM (MFMA bf16): 64 rows x 64 cols per block, 4 waves.
// hs1[i,f] = bf16((x @ W1)[i,f] * dinv[i])  -- PRE-SCALED (agg1 adds directly).
// Block 0 also zeroes sentinel row N (gathered by OOR edge slots in agg1).
__global__ __launch_bounds__(256) void k_gemm1(
        const float* __restrict__ x, const ushort_t* __restrict__ wt,
        const float* __restrict__ dinv, ushort_t* __restrict__ hs1, int N) {
    __shared__ ushort_t xb[64][136];   // x tile, bf16 (+pad -> frag reads <=2-way)
    __shared__ ushort_t wb[64][136];   // W1^T (wb[n][k]), bf16
    int t = threadIdx.x;
    int rbase = blockIdx.x * 64;
    if (blockIdx.x == 0 && t < 8) {    // sentinel row N = zeros (128 B)
        uint4 z = {0u, 0u, 0u, 0u};
        ((uint4*)hs1)[(size_t)N * 8 + t] = z;
    }
    for (int i = t; i < 1024; i += BLK) {       // 4 iters: uint4 copy
        int n = i >> 4, q = i & 15;
        uint4 v = ((const uint4*)wt)[i];
        *(uint4*)&wb[n][8 * q] = v;
    }
    for (int i = t; i < 2048; i += BLK) {
        int r = i >> 5, c4 = i & 31;
        int rr = rbase + r; if (rr >= N) rr = N - 1;
        float4 v = ((const float4*)x)[(size_t)rr * 32 + c4];
        uint2 p;
        p.x = pkbf(v.x, v.y);
        p.y = pkbf(v.z, v.w);
        *(uint2*)&xb[r][4 * c4] = p;
    }
    __syncthreads();
    int w = t >> 6, l = t & 63;
    int lane16 = l & 15, quad = l >> 4;
    int mrow = 16 * w + lane16;
    f32x4 acc0 = {0.f, 0.f, 0.f, 0.f}, acc1 = {0.f, 0.f, 0.f, 0.f};
    f32x4 acc2 = {0.f, 0.f, 0.f, 0.f}, acc3 = {0.f, 0.f, 0.f, 0.f};
#pragma unroll
    for (int kk = 0; kk < 4; ++kk) {
        int k0 = kk * 32 + quad * 8;
        bf16x8 a  = *(const bf16x8*)&xb[mrow][k0];
        bf16x8 b0 = *(const bf16x8*)&wb[lane16][k0];
        bf16x8 b1 = *(const bf16x8*)&wb[lane16 + 16][k0];
        bf16x8 b2 = *(const bf16x8*)&wb[lane16 + 32][k0];
        bf16x8 b3 = *(const bf16x8*)&wb[lane16 + 48][k0];
        acc0 = __builtin_amdgcn_mfma_f32_16x16x32_bf16(a, b0, acc0, 0, 0, 0);
        acc1 = __builtin_amdgcn_mfma_f32_16x16x32_bf16(a, b1, acc1, 0, 0, 0);
        acc2 = __builtin_amdgcn_mfma_f32_16x16x32_bf16(a, b2, acc2, 0, 0, 0);
        acc3 = __builtin_amdgcn_mfma_f32_16x16x32_bf16(a, b3, acc3, 0, 0, 0);
    }
    __syncthreads();
    int orow = 16 * w + quad * 4;   // D: row = quad*4+reg, col = lane16 (+16c)
    float d0 = dinv[min(rbase + orow + 0, N - 1)];
    float d1 = dinv[min(rbase + orow + 1, N - 1)];
    float d2 = dinv[min(rbase + orow + 2, N - 1)];
    float d3 = dinv[min(rbase + orow + 3, N - 1)];
    uint_t u;
    u = pkbf(acc0.x * d0, acc0.y * d1);
    xb[orow + 0][lane16] = (ushort_t)u;  xb[orow + 1][lane16] = (ushort_t)(u >> 16);
    u = pkbf(acc0.z * d2, acc0.w * d3);
    xb[orow + 2][lane16] = (ushort_t)u;  xb[orow + 3][lane16] = (ushort_t)(u >> 16);
    u = pkbf(acc1.x * d0, acc1.y * d1);
    xb[orow + 0][lane16 + 16] = (ushort_t)u;  xb[orow + 1][lane16 + 16] = (ushort_t)(u >> 16);
    u = pkbf(acc1.z * d2, acc1.w * d3);
    xb[orow + 2][lane16 + 16] = (ushort_t)u;  xb[orow + 3][lane16 + 16] = (ushort_t)(u >> 16);
    u = pkbf(acc2.x * d0, acc2.y * d1);
    xb[orow + 0][lane16 + 32] = (ushort_t)u;  xb[orow + 1][lane16 + 32] = (ushort_t)(u >> 16);
    u = pkbf(acc2.z * d2, acc2.w * d3);
    xb[orow + 2][lane16 + 32] = (ushort_t)u;  xb[orow + 3][lane16 + 32] = (ushort_t)(u >> 16);
    u = pkbf(acc3.x * d0, acc3.y * d1);
    xb[orow + 0][lane16 + 48] = (ushort_t)u;  xb[orow + 1][lane16 + 48] = (ushort_t)(u >> 16);
    u = pkbf(acc3.z * d2, acc3.w * d3);
    xb[orow + 2][lane16 + 48] = (ushort_t)u;  xb[orow + 3][lane16 + 48] = (ushort_t)(u >> 16);
    __syncthreads();
    for (int i = t; i < 512; i += BLK) {
        int r = i >> 3, c8 = i & 7;
        int rr = rbase + r;
        if (rr < N) {
            uint4 v = *(const uint4*)&xb[r][8 * c8];
            *(uint4*)&hs1[(size_t)rr * 64 + 8 * c8] = v;
        }
    }
}

// ---- layer 1 aggregation + FUSED layer 2 GEMM. 8 lanes per node, 8 nodes
// per wave, 32 nodes per block. Sentinel-row unconditional gathers; dot2
// accumulate. Epilogue: relu'd a1 rows -> LDS tile -> 4-wave 32x64 @ 64x32
// MFMA -> hs2 (pre-scaled by dinv[row]). hs2 does NOT alias hs1.
__global__ __launch_bounds__(256) void k_agg1(
        const uint_t* __restrict__ hs1, const int* __restrict__ row_ptr,
        const int* __restrict__ deg, const int* __restrict__ csr_src,
        const float* __restrict__ dinv, const float* __restrict__ b1,
        const ushort_t* __restrict__ wt, ushort_t* __restrict__ hs2, int N) {
    __shared__ ushort_t ab[32][72];    // a1 rows, bf16 (+pad)
    __shared__ ushort_t wb2[32][72];   // W2^T (wb2[n][k]), bf16
    int t = threadIdx.x;
    int lane = t & 63;
    int w = t >> 6;
    int g = lane >> 3;   // node sub-index within wave (0..7)
    int c = lane & 7;    // uint4 column: features [8c, 8c+8)
    int rbase = blockIdx.x * 32;
    int node = rbase + w * 8 + g;
    bool alive = node < N;
    int nodeC = alive ? node : N - 1;
    if (blockIdx.x == 0 && t < 4) {    // hs2 sentinel row N = zeros (64 B)
        uint4 z = {0u, 0u, 0u, 0u};
        ((uint4*)hs2)[(size_t)N * 4 + t] = z;
    }
    // stage W2^T: 256 uint4 = 1/thread
    {
        int n = t >> 3, q = t & 7;
        uint4 v = ((const uint4*)(wt + 8192))[t];
        *(uint4*)&wb2[n][8 * q] = v;
    }
    const uint4* H = (const uint4*)hs1;
    float dn = dinv[nodeC];
    int beg = row_ptr[nodeC];
    int tot = alive ? deg[nodeC] : 0;
    uint4 selfv = H[(size_t)nodeC * 8 + c];   // issued early, consumed last
    int gbase = lane & 0x38;                  // first lane of this group
    uint_t blo = BLO, bhi = BHI;
    // wave-uniform chunk count (max degree over the 8 nodes)
    int wtot = tot;
    wtot = max(wtot, __shfl_xor(wtot, 8, 64));
    wtot = max(wtot, __shfl_xor(wtot, 16, 64));
    wtot = max(wtot, __shfl_xor(wtot, 32, 64));
    int nch = (wtot + 7) >> 3;
    float s0 = 0.f, s1 = 0.f, s2 = 0.f, s3 = 0.f;
    float s4 = 0.f, s5 = 0.f, s6 = 0.f, s7 = 0.f;
    for (int i = 0; i < nch; ++i) {
        int base = 8 * i;
        int jal = (base + c < tot) ? csr_src[beg + base + c] : N;  // sentinel
        uint4 vv[8];
#pragma unroll
        for (int e = 0; e < 8; ++e) {         // unconditional gathers
            int j = __shfl(jal, gbase + e, 64);
            vv[e] = H[(size_t)j * 8 + c];
        }
#pragma unroll
        for (int e = 0; e < 8; ++e)           // unconditional dot2 accumulate
            dadd(s0, s1, s2, s3, s4, s5, s6, s7, vv[e], blo, bhi);
    }
    dadd(s0, s1, s2, s3, s4, s5, s6, s7, selfv, blo, bhi);   // self-loop
    // a1 row (bias + relu) -> LDS tile (dead nodes write zeros)
    {
        const float4* B = (const float4*)b1;
        float4 bv0 = B[2 * c], bv1 = B[2 * c + 1];
        uint4 o = {0u, 0u, 0u, 0u};
        if (alive) {
            float o0 = fmaxf(fmaf(s0, dn, bv0.x), 0.f);
            float o1 = fmaxf(fmaf(s1, dn, bv0.y), 0.f);
            float o2 = fmaxf(fmaf(s2, dn, bv0.z), 0.f);
            float o3 = fmaxf(fmaf(s3, dn, bv0.w), 0.f);
            float o4 = fmaxf(fmaf(s4, dn, bv1.x), 0.f);
            float o5 = fmaxf(fmaf(s5, dn, bv1.y), 0.f);
            float o6 = fmaxf(fmaf(s6, dn, bv1.z), 0.f);
            float o7 = fmaxf(fmaf(s7, dn, bv1.w), 0.f);
            o.x = pkbf(o0, o1);
            o.y = pkbf(o2, o3);
            o.z = pkbf(o4, o5);
            o.w = pkbf(o6, o7);
        }
        *(uint4*)&ab[w * 8 + g][8 * c] = o;
    }
    __syncthreads();
    // fused mini-GEMM: 32x64 @ 64x32 (k_gemm2 pattern). wave w: row stripe
    // rt=w&1 (16 rows), col stripe ct=w>>1 (16 cols), K=64 -> 2 MFMA.
    int lane16 = lane & 15, quad = lane >> 4;
    int rt = w & 1, ct = w >> 1;
    int mrow = 16 * rt + lane16;
    f32x4 acc = {0.f, 0.f, 0.f, 0.f};
#pragma unroll
    for (int kk = 0; kk < 2; ++kk) {
        int k0 = kk * 32 + quad * 8;
        bf16x8 a = *(const bf16x8*)&ab[mrow][k0];
        bf16x8 b = *(const bf16x8*)&wb2[16 * ct + lane16][k0];
        acc = __builtin_amdgcn_mfma_f32_16x16x32_bf16(a, b, acc, 0, 0, 0);
    }
    __syncthreads();
    int orow = 16 * rt + quad * 4;   // D: row = quad*4+reg, col = 16ct+lane16
    int ocol = 16 * ct + lane16;
    float d0 = dinv[min(rbase + orow + 0, N - 1)];
    float d1 = dinv[min(rbase + orow + 1, N - 1)];
    float d2 = dinv[min(rbase + orow + 2, N - 1)];
    float d3 = dinv[min(rbase + orow + 3, N - 1)];
    uint_t u;
    u = pkbf(acc.x * d0, acc.y * d1);
    ab[orow + 0][ocol] = (ushort_t)u;  ab[orow + 1][ocol] = (ushort_t)(u >> 16);
    u = pkbf(acc.z * d2, acc.w * d3);
    ab[orow + 2][ocol] = (ushort_t)u;  ab[orow + 3][ocol] = (ushort_t)(u >> 16);
    __syncthreads();
    for (int i = t; i < 128; i += BLK) {
        int r = i >> 2, c4 = i & 3;
        int rr = rbase + r;
        if (rr < N) {
            uint4 v = *(const uint4*)&ab[r][8 * c4];
            ((uint4*)hs2)[(size_t)rr * 4 + c4] = v;
        }
    }
}

// ---- layer 2 aggregation: 4 lanes per node, 16 nodes per wave; sentinel
// unconditional form; dot2 accumulate.
__global__ void k_agg2(const uint_t* __restrict__ hs2, const int* __restrict__ row_ptr,
                       const int* __restrict__ deg, const int* __restrict__ csr_src,
                       const float* __restrict__ dinv, const float* __restrict__ b2,
                       float* __restrict__ out, int N) {
    int lane = threadIdx.x & 63;
    int g = lane >> 2;   // node sub-index within wave (0..15)
    int c = lane & 3;    // uint4 column: features [8c, 8c+8)
    int wavebase = ((blockIdx.x * blockDim.x + threadIdx.x) >> 6) * 16;
    int node = wavebase + g;
    bool alive = node < N;
    int nodeC = alive ? node : N - 1;
    const uint4* H = (const uint4*)hs2;
    float dn = dinv[nodeC];
    int beg = row_ptr[nodeC];
    int tot = alive ? deg[nodeC] : 0;
    uint4 selfv = H[(size_t)nodeC * 4 + c];   // issued early, consumed last
    int gbase = lane & 0x3C;                  // first lane of this group
    uint_t blo = BLO, bhi = BHI;
    int wtot = tot;
    wtot = max(wtot, __shfl_xor(wtot, 4, 64));
    wtot = max(wtot, __shfl_xor(wtot, 8, 64));
    wtot = max(wtot, __shfl_xor(wtot, 16, 64));
    wtot = max(wtot, __shfl_xor(wtot, 32, 64));
    int nch = (wtot + 3) >> 2;
    float s0 = 0.f, s1 = 0.f, s2 = 0.f, s3 = 0.f;
    float s4 = 0.f, s5 = 0.f, s6 = 0.f, s7 = 0.f;
    for (int i = 0; i < nch; ++i) {
        int base = 4 * i;
        int jal = (base + c < tot) ? csr_src[beg + base + c] : N;  // sentinel
        uint4 vv[4];
#pragma unroll
        for (int e = 0; e < 4; ++e) {         // unconditional gathers
            int j = __shfl(jal, gbase + e, 64);
            vv[e] = H[(size_t)j * 4 + c];
        }
#pragma unroll
        for (int e = 0; e < 4; ++e)           // unconditional dot2 accumulate
            dadd(s0, s1, s2, s3, s4, s5, s6, s7, vv[e], blo, bhi);
    }
    dadd(s0, s1, s2, s3, s4, s5, s6, s7, selfv, blo, bhi);   // self-loop
    if (alive) {
        const float4* B = (const float4*)b2;
        float4 bv0 = B[2 * c], bv1 = B[2 * c + 1];
        float4 o0, o1;
        o0.x = fmaf(s0, dn, bv0.x);
        o0.y = fmaf(s1, dn, bv0.y);
        o0.z = fmaf(s2, dn, bv0.z);
        o0.w = fmaf(s3, dn, bv0.w);
        o1.x = fmaf(s4, dn, bv1.x);
        o1.y = fmaf(s5, dn, bv1.y);
        o1.z = fmaf(s6, dn, bv1.z);
        o1.w = fmaf(s7, dn, bv1.w);
        float4* O = (float4*)out;
        O[(size_t)node * 8 + 2 * c] = o0;
        O[(size_t)node * 8 + 2 * c + 1] = o1;
    }
}

extern "C" void kernel_launch(void* const* d_in, const int* in_sizes, int n_in,
                              void* d_out, int out_size, void* d_ws, size_t ws_size,
                              hipStream_t stream) {
    const float* x  = (const float*)d_in[0];
    const int*   idx = (const int*)d_in[1];
    const float* W1 = (const float*)d_in[2];
    const float* b1 = (const float*)d_in[3];
    const float* W2 = (const float*)d_in[4];
    const float* b2 = (const float*)d_in[5];
    float* out = (float*)d_out;

    const int N = in_sizes[0] / 128;   // 100000 (< 2^17, required by packing)
    const int E = in_sizes[1] / 2;     // 1600000
    const int nbuck = (N + NPB - 1) >> BSHIFT;        // 196 (<= NBMAX)
    const int PB = (E + BLK * EPT - 1) / (BLK * EPT); // 782

    // workspace layout (256B aligned)
    char* ws = (char*)d_ws;
    size_t off = 0;
    auto alloc = [&](size_t bytes) -> char* {
        char* p = ws + off;
        off = (off + bytes + 255) & ~(size_t)255;
        return p;
    };
    float* dinv     = (float*)alloc((size_t)N * 4);
    int*   row_ptr  = (int*)alloc((size_t)N * 4);
    int*   deg      = (int*)alloc((size_t)N * 4);
    int*   bcursor  = (int*)alloc((size_t)nbuck * 4);
    ushort_t* wt    = (ushort_t*)alloc((size_t)(8192 + 2048) * 2);  // W1^T,W2^T bf16
    int*   csr_src  = (int*)alloc((size_t)nbuck * SLOTB * 4);   // 8.0 MB
    size_t ep_bytes = (size_t)nbuck * SLOTB * 4;                // 8.0 MB
    size_t h1_bytes = (size_t)(N + 1) * 64 * 2;                 // 12.8 MB (+sentinel)
    int*   edge_part = (int*)alloc(ep_bytes > h1_bytes ? ep_bytes : h1_bytes);
    ushort_t* hs2   = (ushort_t*)alloc((size_t)(N + 1) * 32 * 2);  // 6.4 MB (+sentinel)
    ushort_t* hs1   = (ushort_t*)edge_part;   // alias: edge_part dead after k_csr

    hipMemsetAsync(bcursor, 0, (size_t)nbuck * 4, stream);
    k_part<<<PB + 1, BLK, 0, stream>>>(idx, bcursor, edge_part, W1, W2, wt,
                                       E, nbuck, PB);
    k_csr<<<nbuck, BLKC, 0, stream>>>(edge_part, bcursor, row_ptr, deg, dinv,
                                      csr_src, N, nbuck);
    k_gemm1<<<(N + 63) / 64, BLK, 0, stream>>>(x, wt, dinv, hs1, N);
    k_agg1<<<(N * 8 + BLK - 1) / BLK, BLK, 0, stream>>>(
        (const uint_t*)hs1, row_ptr, deg, csr_src, dinv, b1, wt, hs2, N);
    k_agg2<<<(N * 4 + BLK - 1) / BLK, BLK, 0, stream>>>(
        (const uint_t*)hs2, row_ptr, deg, csr_src, dinv, b2, out, N);
}

// Round 11
// 200.934 us; speedup vs baseline: 1.0116x; 1.0116x over previous
//
#include <hip/hip_runtime.h>

// GCN 2-layer: x[N,128] -> GCNConv(W1[128,64], b1) -> ReLU -> GCNConv(W2[64,32], b2)
// norm = dinv[src]*dinv[dst] factorized. Bucketed multisplit build (R4), bf16
// intermediates (R5), MFMA gemms (R8), dense per-bucket edge segments (R10),
// pre-scaled hs (R11), group-per-node aggs (R12), batched gather issue (R13),
// rank capture (R14), pk-cvt + pre-converted W + 2-barrier scan (R15/R16),
// 512-node buckets + sentinel unconditional aggs (R17/R18), gemm2 fused into
// agg1 epilogue (R19).
// R20 (REVERTED in R21): v_dot2_f32_bf16 accumulate regressed 199.8->203.3 us
// -- dot2 is not full-rate like v_pk_add_f32; 8 dot-pipe ops lost to 12
// packed-pipe ops. R21 restores R19's unpack+pk_add path exactly.

#define BLK 256
#define BLKC 1024        // k_csr block size
#define EPT 8            // edges/thread in k_part
#define CITER 10         // k_csr max edges/thread = SLOTB/BLKC
#define BSHIFT 9         // nodes per bucket
#define NPB 512          // 1 << BSHIFT
#define SLOTB 10240      // edge slots per bucket; lambda~8.2K, ~23 sigma
#define NBMAX 256        // >= nbuck = ceil(N/NPB) = 196

typedef unsigned int uint_t;
typedef unsigned short ushort_t;
typedef __attribute__((ext_vector_type(2))) float v2f;      // v_pk_* pair
typedef __attribute__((ext_vector_type(8))) short bf16x8;   // MFMA A/B frag
typedef __attribute__((ext_vector_type(4))) float f32x4;    // MFMA C/D frag

// paired RNE f32->bf16: lo -> bits[15:0], hi -> bits[31:16] (1 VALU op)
__device__ __forceinline__ uint_t pkbf(float lo, float hi) {
    uint_t r;
    asm("v_cvt_pk_bf16_f32 %0, %1, %2" : "=v"(r) : "v"(lo), "v"(hi));
    return r;
}

// 8 bf16 (uint4) += into 4 float2 accumulators (v_pk_add_f32 path)
__device__ __forceinline__ void pkadd(v2f& a0, v2f& a1, v2f& a2, v2f& a3, uint4 v) {
    v2f p;
    p.x = __uint_as_float(v.x << 16); p.y = __uint_as_float(v.x & 0xffff0000u); a0 += p;
    p.x = __uint_as_float(v.y << 16); p.y = __uint_as_float(v.y & 0xffff0000u); a1 += p;
    p.x = __uint_as_float(v.z << 16); p.y = __uint_as_float(v.z & 0xffff0000u); a2 += p;
    p.x = __uint_as_float(v.w << 16); p.y = __uint_as_float(v.w & 0xffff0000u); a3 += p;
}

// int64-layout detection (wave-uniform, L2-hot)
__device__ __forceinline__ bool detect64(const int* __restrict__ idx) {
    int z = 0;
#pragma unroll
    for (int i = 1; i < 32; i += 2) z |= idx[i];
    return z == 0;
}

// ---- build pass 1: partition edges into DENSE per-bucket segments.
// Rank captured from the counting atomicAdd; placement pass has no atomics.
// Block PB (extra) converts W1->W1^T bf16 [64][128] and W2->W2^T bf16 [32][64].
__global__ void k_part(const int* __restrict__ idx, int* __restrict__ bcursor,
                       int* __restrict__ edge_part,
                       const float* __restrict__ W1, const float* __restrict__ W2,
                       ushort_t* __restrict__ wt, int E, int nbuck, int PB) {
    if (blockIdx.x == PB) {          // W-conversion block
        int t = threadIdx.x;
        int n = t >> 2, q = t & 3;   // W1^T row n (0..63), k-block q (32 k)
        uint_t buf[16];
#pragma unroll
        for (int i = 0; i < 16; ++i) {
            float a = W1[(size_t)(32 * q + 2 * i) * 64 + n];
            float b = W1[(size_t)(32 * q + 2 * i + 1) * 64 + n];
            buf[i] = pkbf(a, b);
        }
#pragma unroll
        for (int i = 0; i < 4; ++i)
            ((uint4*)wt)[(size_t)n * 16 + q * 4 + i] = *(uint4*)&buf[4 * i];
        if (t < 128) {               // W2^T row n2 (0..31), k-block q2 (16 k)
            int n2 = t >> 2, q2 = t & 3;
            uint_t b2[8];
#pragma unroll
            for (int i = 0; i < 8; ++i) {
                float a = W2[(size_t)(16 * q2 + 2 * i) * 32 + n2];
                float b = W2[(size_t)(16 * q2 + 2 * i + 1) * 32 + n2];
                b2[i] = pkbf(a, b);
            }
#pragma unroll
            for (int i = 0; i < 2; ++i)
                ((uint4*)(wt + 8192))[(size_t)n2 * 8 + q2 * 2 + i] = *(uint4*)&b2[4 * i];
        }
        return;
    }
    __shared__ int h[NBMAX];
    __shared__ int rb[NBMAX];
    bool is64 = detect64(idx);
    int t = threadIdx.x, blk = blockIdx.x;
    for (int i = t; i < nbuck; i += BLK) h[i] = 0;
    __syncthreads();
    int base = blk * (BLK * EPT) + t;
    int dst[EPT], src[EPT], rk[EPT];
#pragma unroll
    for (int k = 0; k < EPT; ++k) {
        int e = base + k * BLK;
        if (e < E) {
            if (is64) {
                uint2 dv = ((const uint2*)idx)[(size_t)E + e];   // int64 dst[e]
                uint2 sv = ((const uint2*)idx)[e];               // int64 src[e]
                dst[k] = (int)dv.x;
                src[k] = (int)sv.x;
            } else {
                dst[k] = idx[E + e];
                src[k] = idx[e];
            }
            rk[k] = atomicAdd(&h[dst[k] >> BSHIFT], 1);
        } else {
            dst[k] = -1;
        }
    }
    __syncthreads();
    for (int i = t; i < nbuck; i += BLK) {
        int c = h[i];
        rb[i] = c ? atomicAdd(&bcursor[i], c) : 0;
    }
    __syncthreads();
#pragma unroll
    for (int k = 0; k < EPT; ++k) {
        if (dst[k] >= 0) {
            int b = dst[k] >> BSHIFT;
            edge_part[(size_t)b * SLOTB + rb[b] + rk[k]] =
                src[k] | ((dst[k] & (NPB - 1)) << 17);
        }
    }
}

// ---- build pass 2: one 1024-thread block per 512-node bucket; emits
// row_ptr, deg, dinv, csr_src. Single edge sweep with rank capture;
// shfl wave-scan over 512 entries (2 barriers).
__global__ __launch_bounds__(BLKC) void k_csr(
        const int* __restrict__ edge_part, const int* __restrict__ bcursor,
        int* __restrict__ row_ptr, int* __restrict__ deg, float* __restrict__ dinv,
        int* __restrict__ csr_src, int N, int nbuck) {
    __shared__ int cnt[NPB];
    __shared__ int off[NPB];
    __shared__ int wsum[8];
    int b = blockIdx.x, t = threadIdx.x;
    int node0 = b << BSHIFT;
    int nn = min(NPB, N - node0);
    int m = bcursor[b];                   // total edges in this bucket
    size_t ebase = (size_t)b * SLOTB;
    if (t < NPB) cnt[t] = 0;
    __syncthreads();
    int pp[CITER], rr[CITER];
#pragma unroll
    for (int it = 0; it < CITER; ++it) {
        int e = t + it * BLKC;
        if (e < m) {
            int p = edge_part[ebase + e];
            pp[it] = p;
            rr[it] = atomicAdd(&cnt[((unsigned)p) >> 17], 1);
        }
    }
    __syncthreads();
    // scan over 512 entries: waves 0..7 shfl-scan, 8-entry wave-sum scan
    int cown = 0, xi = 0;
    if (t < NPB) {
        cown = cnt[t];
        xi = cown;
#pragma unroll
        for (int d = 1; d < 64; d <<= 1) {
            int y = __shfl_up(xi, d, 64);
            if ((t & 63) >= d) xi += y;
        }
        if ((t & 63) == 63) wsum[t >> 6] = xi;
    }
    __syncthreads();
    if (t < 8) {
        int wv = wsum[t];
#pragma unroll
        for (int d = 1; d < 8; d <<= 1) {
            int y = __shfl_up(wv, d, 64);
            if (t >= d) wv += y;
        }
        wsum[t] = wv;   // inclusive wave sums
    }
    __syncthreads();
    if (t < NPB) {
        int excl = xi - cown + ((t >= 64) ? wsum[(t >> 6) - 1] : 0);
        off[t] = excl;
        if (t < nn) {
            row_ptr[node0 + t] = (int)(ebase + excl);
            deg[node0 + t] = cown;
            dinv[node0 + t] = rsqrtf((float)(cown + 1));  // +1 self-loop
        }
    }
    __syncthreads();
#pragma unroll
    for (int it = 0; it < CITER; ++it) {
        int e = t + it * BLKC;
        if (e < m) {
            int p = pp[it];
            int dlo = ((unsigned)p) >> 17;
            csr_src[ebase + off[dlo] + rr[it]] = p & 0x1FFFF;
        }
    }
}

// ---- layer 1 GEMM (MFMA bf16): 64 rows x 64 cols per block, 4 waves.
// hs1[i,f] = bf16((x @ W1)[i,f] * dinv[i])  -- PRE-SCALED (agg1 adds directly).
// Block 0 also zeroes sentinel row N (gathered by OOR edge slots in agg1).
__global__ __launch_bounds__(256) void k_gemm1(
        const float* __restrict__ x, const ushort_t* __restrict__ wt,
        const float* __restrict__ dinv, ushort_t* __restrict__ hs1, int N) {
    __shared__ ushort_t xb[64][136];   // x tile, bf16 (+pad -> frag reads <=2-way)
    __shared__ ushort_t wb[64][136];   // W1^T (wb[n][k]), bf16
    int t = threadIdx.x;
    int rbase = blockIdx.x * 64;
    if (blockIdx.x == 0 && t < 8) {    // sentinel row N = zeros (128 B)
        uint4 z = {0u, 0u, 0u, 0u};
        ((uint4*)hs1)[(size_t)N * 8 + t] = z;
    }
    for (int i = t; i < 1024; i += BLK) {       // 4 iters: uint4 copy
        int n = i >> 4, q = i & 15;
        uint4 v = ((const uint4*)wt)[i];
        *(uint4*)&wb[n][8 * q] = v;
    }
    for (int i = t; i < 2048; i += BLK) {
        int r = i >> 5, c4 = i & 31;
        int rr = rbase + r; if (rr >= N) rr = N - 1;
        float4 v = ((const float4*)x)[(size_t)rr * 32 + c4];
        uint2 p;
        p.x = pkbf(v.x, v.y);
        p.y = pkbf(v.z, v.w);
        *(uint2*)&xb[r][4 * c4] = p;
    }
    __syncthreads();
    int w = t >> 6, l = t & 63;
    int lane16 = l & 15, quad = l >> 4;
    int mrow = 16 * w + lane16;
    f32x4 acc0 = {0.f, 0.f, 0.f, 0.f}, acc1 = {0.f, 0.f, 0.f, 0.f};
    f32x4 acc2 = {0.f, 0.f, 0.f, 0.f}, acc3 = {0.f, 0.f, 0.f, 0.f};
#pragma unroll
    for (int kk = 0; kk < 4; ++kk) {
        int k0 = kk * 32 + quad * 8;
        bf16x8 a  = *(const bf16x8*)&xb[mrow][k0];
        bf16x8 b0 = *(const bf16x8*)&wb[lane16][k0];
        bf16x8 b1 = *(const bf16x8*)&wb[lane16 + 16][k0];
        bf16x8 b2 = *(const bf16x8*)&wb[lane16 + 32][k0];
        bf16x8 b3 = *(const bf16x8*)&wb[lane16 + 48][k0];
        acc0 = __builtin_amdgcn_mfma_f32_16x16x32_bf16(a, b0, acc0, 0, 0, 0);
        acc1 = __builtin_amdgcn_mfma_f32_16x16x32_bf16(a, b1, acc1, 0, 0, 0);
        acc2 = __builtin_amdgcn_mfma_f32_16x16x32_bf16(a, b2, acc2, 0, 0, 0);
        acc3 = __builtin_amdgcn_mfma_f32_16x16x32_bf16(a, b3, acc3, 0, 0, 0);
    }
    __syncthreads();
    int orow = 16 * w + quad * 4;   // D: row = quad*4+reg, col = lane16 (+16c)
    float d0 = dinv[min(rbase + orow + 0, N - 1)];
    float d1 = dinv[min(rbase + orow + 1, N - 1)];
    float d2 = dinv[min(rbase + orow + 2, N - 1)];
    float d3 = dinv[min(rbase + orow + 3, N - 1)];
    uint_t u;
    u = pkbf(acc0.x * d0, acc0.y * d1);
    xb[orow + 0][lane16] = (ushort_t)u;  xb[orow + 1][lane16] = (ushort_t)(u >> 16);
    u = pkbf(acc0.z * d2, acc0.w * d3);
    xb[orow + 2][lane16] = (ushort_t)u;  xb[orow + 3][lane16] = (ushort_t)(u >> 16);
    u = pkbf(acc1.x * d0, acc1.y * d1);
    xb[orow + 0][lane16 + 16] = (ushort_t)u;  xb[orow + 1][lane16 + 16] = (ushort_t)(u >> 16);
    u = pkbf(acc1.z * d2, acc1.w * d3);
    xb[orow + 2][lane16 + 16] = (ushort_t)u;  xb[orow + 3][lane16 + 16] = (ushort_t)(u >> 16);
    u = pkbf(acc2.x * d0, acc2.y * d1);
    xb[orow + 0][lane16 + 32] = (ushort_t)u;  xb[orow + 1][lane16 + 32] = (ushort_t)(u >> 16);
    u = pkbf(acc2.z * d2, acc2.w * d3);
    xb[orow + 2][lane16 + 32] = (ushort_t)u;  xb[orow + 3][lane16 + 32] = (ushort_t)(u >> 16);
    u = pkbf(acc3.x * d0, acc3.y * d1);
    xb[orow + 0][lane16 + 48] = (ushort_t)u;  xb[orow + 1][lane16 + 48] = (ushort_t)(u >> 16);
    u = pkbf(acc3.z * d2, acc3.w * d3);
    xb[orow + 2][lane16 + 48] = (ushort_t)u;  xb[orow + 3][lane16 + 48] = (ushort_t)(u >> 16);
    __syncthreads();
    for (int i = t; i < 512; i += BLK) {
        int r = i >> 3, c8 = i & 7;
        int rr = rbase + r;
        if (rr < N) {
            uint4 v = *(const uint4*)&xb[r][8 * c8];
            *(uint4*)&hs1[(size_t)rr * 64 + 8 * c8] = v;
        }
    }
}

// ---- layer 1 aggregation + FUSED layer 2 GEMM. 8 lanes per node, 8 nodes
// per wave, 32 nodes per block. Sentinel-row unconditional gathers. Epilogue:
// relu'd a1 rows -> LDS tile -> 4-wave 32x64 @ 64x32 MFMA -> hs2 (pre-scaled
// by dinv[row]). hs2 does NOT alias hs1.
__global__ __launch_bounds__(256) void k_agg1(
        const uint_t* __restrict__ hs1, const int* __restrict__ row_ptr,
        const int* __restrict__ deg, const int* __restrict__ csr_src,
        const float* __restrict__ dinv, const float* __restrict__ b1,
        const ushort_t* __restrict__ wt, ushort_t* __restrict__ hs2, int N) {
    __shared__ ushort_t ab[32][72];    // a1 rows, bf16 (+pad)
    __shared__ ushort_t wb2[32][72];   // W2^T (wb2[n][k]), bf16
    int t = threadIdx.x;
    int lane = t & 63;
    int w = t >> 6;
    int g = lane >> 3;   // node sub-index within wave (0..7)
    int c = lane & 7;    // uint4 column: features [8c, 8c+8)
    int rbase = blockIdx.x * 32;
    int node = rbase + w * 8 + g;
    bool alive = node < N;
    int nodeC = alive ? node : N - 1;
    if (blockIdx.x == 0 && t < 4) {    // hs2 sentinel row N = zeros (64 B)
        uint4 z = {0u, 0u, 0u, 0u};
        ((uint4*)hs2)[(size_t)N * 4 + t] = z;
    }
    // stage W2^T: 256 uint4 = 1/thread
    {
        int n = t >> 3, q = t & 7;
        uint4 v = ((const uint4*)(wt + 8192))[t];
        *(uint4*)&wb2[n][8 * q] = v;
    }
    const uint4* H = (const uint4*)hs1;
    float dn = dinv[nodeC];
    int beg = row_ptr[nodeC];
    int tot = alive ? deg[nodeC] : 0;
    uint4 selfv = H[(size_t)nodeC * 8 + c];   // issued early, consumed last
    int gbase = lane & 0x38;                  // first lane of this group
    // wave-uniform chunk count (max degree over the 8 nodes)
    int wtot = tot;
    wtot = max(wtot, __shfl_xor(wtot, 8, 64));
    wtot = max(wtot, __shfl_xor(wtot, 16, 64));
    wtot = max(wtot, __shfl_xor(wtot, 32, 64));
    int nch = (wtot + 7) >> 3;
    v2f a0 = {0.f, 0.f}, a1_ = {0.f, 0.f}, a2 = {0.f, 0.f}, a3 = {0.f, 0.f};
    for (int i = 0; i < nch; ++i) {
        int base = 8 * i;
        int jal = (base + c < tot) ? csr_src[beg + base + c] : N;  // sentinel
        uint4 vv[8];
#pragma unroll
        for (int e = 0; e < 8; ++e) {         // unconditional gathers
            int j = __shfl(jal, gbase + e, 64);
            vv[e] = H[(size_t)j * 8 + c];
        }
#pragma unroll
        for (int e = 0; e < 8; ++e)           // unconditional accumulate
            pkadd(a0, a1_, a2, a3, vv[e]);
    }
    pkadd(a0, a1_, a2, a3, selfv);            // self-loop
    // a1 row (bias + relu) -> LDS tile (dead nodes write zeros)
    {
        const float4* B = (const float4*)b1;
        float4 bv0 = B[2 * c], bv1 = B[2 * c + 1];
        uint4 o = {0u, 0u, 0u, 0u};
        if (alive) {
            float o0 = fmaxf(fmaf(a0.x, dn, bv0.x), 0.f);
            float o1 = fmaxf(fmaf(a0.y, dn, bv0.y), 0.f);
            float o2 = fmaxf(fmaf(a1_.x, dn, bv0.z), 0.f);
            float o3 = fmaxf(fmaf(a1_.y, dn, bv0.w), 0.f);
            float o4 = fmaxf(fmaf(a2.x, dn, bv1.x), 0.f);
            float o5 = fmaxf(fmaf(a2.y, dn, bv1.y), 0.f);
            float o6 = fmaxf(fmaf(a3.x, dn, bv1.z), 0.f);
            float o7 = fmaxf(fmaf(a3.y, dn, bv1.w), 0.f);
            o.x = pkbf(o0, o1);
            o.y = pkbf(o2, o3);
            o.z = pkbf(o4, o5);
            o.w = pkbf(o6, o7);
        }
        *(uint4*)&ab[w * 8 + g][8 * c] = o;
    }
    __syncthreads();
    // fused mini-GEMM: 32x64 @ 64x32 (k_gemm2 pattern). wave w: row stripe
    // rt=w&1 (16 rows), col stripe ct=w>>1 (16 cols), K=64 -> 2 MFMA.
    int lane16 = lane & 15, quad = lane >> 4;
    int rt = w & 1, ct = w >> 1;
    int mrow = 16 * rt + lane16;
    f32x4 acc = {0.f, 0.f, 0.f, 0.f};
#pragma unroll
    for (int kk = 0; kk < 2; ++kk) {
        int k0 = kk * 32 + quad * 8;
        bf16x8 a = *(const bf16x8*)&ab[mrow][k0];
        bf16x8 b = *(const bf16x8*)&wb2[16 * ct + lane16][k0];
        acc = __builtin_amdgcn_mfma_f32_16x16x32_bf16(a, b, acc, 0, 0, 0);
    }
    __syncthreads();
    int orow = 16 * rt + quad * 4;   // D: row = quad*4+reg, col = 16ct+lane16
    int ocol = 16 * ct + lane16;
    float d0 = dinv[min(rbase + orow + 0, N - 1)];
    float d1 = dinv[min(rbase + orow + 1, N - 1)];
    float d2 = dinv[min(rbase + orow + 2, N - 1)];
    float d3 = dinv[min(rbase + orow + 3, N - 1)];
    uint_t u;
    u = pkbf(acc.x * d0, acc.y * d1);
    ab[orow + 0][ocol] = (ushort_t)u;  ab[orow + 1][ocol] = (ushort_t)(u >> 16);
    u = pkbf(acc.z * d2, acc.w * d3);
    ab[orow + 2][ocol] = (ushort_t)u;  ab[orow + 3][ocol] = (ushort_t)(u >> 16);
    __syncthreads();
    for (int i = t; i < 128; i += BLK) {
        int r = i >> 2, c4 = i & 3;
        int rr = rbase + r;
        if (rr < N) {
            uint4 v = *(const uint4*)&ab[r][8 * c4];
            ((uint4*)hs2)[(size_t)rr * 4 + c4] = v;
        }
    }
}

// ---- layer 2 aggregation: 4 lanes per node, 16 nodes per wave; sentinel
// unconditional form.
__global__ void k_agg2(const uint_t* __restrict__ hs2, const int* __restrict__ row_ptr,
                       const int* __restrict__ deg, const int* __restrict__ csr_src,
                       const float* __restrict__ dinv, const float* __restrict__ b2,
                       float* __restrict__ out, int N) {
    int lane = threadIdx.x & 63;
    int g = lane >> 2;   // node sub-index within wave (0..15)
    int c = lane & 3;    // uint4 column: features [8c, 8c+8)
    int wavebase = ((blockIdx.x * blockDim.x + threadIdx.x) >> 6) * 16;
    int node = wavebase + g;
    bool alive = node < N;
    int nodeC = alive ? node : N - 1;
    const uint4* H = (const uint4*)hs2;
    float dn = dinv[nodeC];
    int beg = row_ptr[nodeC];
    int tot = alive ? deg[nodeC] : 0;
    uint4 selfv = H[(size_t)nodeC * 4 + c];   // issued early, consumed last
    int gbase = lane & 0x3C;                  // first lane of this group
    int wtot = tot;
    wtot = max(wtot, __shfl_xor(wtot, 4, 64));
    wtot = max(wtot, __shfl_xor(wtot, 8, 64));
    wtot = max(wtot, __shfl_xor(wtot, 16, 64));
    wtot = max(wtot, __shfl_xor(wtot, 32, 64));
    int nch = (wtot + 3) >> 2;
    v2f a0 = {0.f, 0.f}, a1_ = {0.f, 0.f}, a2 = {0.f, 0.f}, a3 = {0.f, 0.f};
    for (int i = 0; i < nch; ++i) {
        int base = 4 * i;
        int jal = (base + c < tot) ? csr_src[beg + base + c] : N;  // sentinel
        uint4 vv[4];
#pragma unroll
        for (int e = 0; e < 4; ++e) {         // unconditional gathers
            int j = __shfl(jal, gbase + e, 64);
            vv[e] = H[(size_t)j * 4 + c];
        }
#pragma unroll
        for (int e = 0; e < 4; ++e)           // unconditional accumulate
            pkadd(a0, a1_, a2, a3, vv[e]);
    }
    pkadd(a0, a1_, a2, a3, selfv);            // self-loop
    if (alive) {
        const float4* B = (const float4*)b2;
        float4 bv0 = B[2 * c], bv1 = B[2 * c + 1];
        float4 o0, o1;
        o0.x = fmaf(a0.x, dn, bv0.x);
        o0.y = fmaf(a0.y, dn, bv0.y);
        o0.z = fmaf(a1_.x, dn, bv0.z);
        o0.w = fmaf(a1_.y, dn, bv0.w);
        o1.x = fmaf(a2.x, dn, bv1.x);
        o1.y = fmaf(a2.y, dn, bv1.y);
        o1.z = fmaf(a3.x, dn, bv1.z);
        o1.w = fmaf(a3.y, dn, bv1.w);
        float4* O = (float4*)out;
        O[(size_t)node * 8 + 2 * c] = o0;
        O[(size_t)node * 8 + 2 * c + 1] = o1;
    }
}

extern "C" void kernel_launch(void* const* d_in, const int* in_sizes, int n_in,
                              void* d_out, int out_size, void* d_ws, size_t ws_size,
                              hipStream_t stream) {
    const float* x  = (const float*)d_in[0];
    const int*   idx = (const int*)d_in[1];
    const float* W1 = (const float*)d_in[2];
    const float* b1 = (const float*)d_in[3];
    const float* W2 = (const float*)d_in[4];
    const float* b2 = (const float*)d_in[5];
    float* out = (float*)d_out;

    const int N = in_sizes[0] / 128;   // 100000 (< 2^17, required by packing)
    const int E = in_sizes[1] / 2;     // 1600000
    const int nbuck = (N + NPB - 1) >> BSHIFT;        // 196 (<= NBMAX)
    const int PB = (E + BLK * EPT - 1) / (BLK * EPT); // 782

    // workspace layout (256B aligned)
    char* ws = (char*)d_ws;
    size_t off = 0;
    auto alloc = [&](size_t bytes) -> char* {
        char* p = ws + off;
        off = (off + bytes + 255) & ~(size_t)255;
        return p;
    };
    float* dinv     = (float*)alloc((size_t)N * 4);
    int*   row_ptr  = (int*)alloc((size_t)N * 4);
    int*   deg      = (int*)alloc((size_t)N * 4);
    int*   bcursor  = (int*)alloc((size_t)nbuck * 4);
    ushort_t* wt    = (ushort_t*)alloc((size_t)(8192 + 2048) * 2);  // W1^T,W2^T bf16
    int*   csr_src  = (int*)alloc((size_t)nbuck * SLOTB * 4);   // 8.0 MB
    size_t ep_bytes = (size_t)nbuck * SLOTB * 4;                // 8.0 MB
    size_t h1_bytes = (size_t)(N + 1) * 64 * 2;                 // 12.8 MB (+sentinel)
    int*   edge_part = (int*)alloc(ep_bytes > h1_bytes ? ep_bytes : h1_bytes);
    ushort_t* hs2   = (ushort_t*)alloc((size_t)(N + 1) * 32 * 2);  // 6.4 MB (+sentinel)
    ushort_t* hs1   = (ushort_t*)edge_part;   // alias: edge_part dead after k_csr

    hipMemsetAsync(bcursor, 0, (size_t)nbuck * 4, stream);
    k_part<<<PB + 1, BLK, 0, stream>>>(idx, bcursor, edge_part, W1, W2, wt,
                                       E, nbuck, PB);
    k_csr<<<nbuck, BLKC, 0, stream>>>(edge_part, bcursor, row_ptr, deg, dinv,
                                      csr_src, N, nbuck);
    k_gemm1<<<(N + 63) / 64, BLK, 0, stream>>>(x, wt, dinv, hs1, N);
    k_agg1<<<(N * 8 + BLK - 1) / BLK, BLK, 0, stream>>>(
        (const uint_t*)hs1, row_ptr, deg, csr_src, dinv, b1, wt, hs2, N);
    k_agg2<<<(N * 4 + BLK - 1) / BLK, BLK, 0, stream>>>(
        (const uint_t*)hs2, row_ptr, deg, csr_src, dinv, b2, out, N);
}